// Round 3
// baseline (294.701 us; speedup 1.0000x reference)
//
#include <hip/hip_runtime.h>

// YOLO layer: (64, 3*10, 152, 152) fp32 -> (64, 3*152*152, 10) fp32
// channel-planar -> channel-interleaved with sigmoid/exp/affine decode.
// Memory-bound: ~177 MB in + ~177 MB out => ~56 us roofline at 6.3 TB/s.

#define NA 3
#define NC 3
#define GSZ 152
#define GG (GSZ * GSZ)        // 23104
#define CH 10                 // 7 + NC
#define BATCH 64
#define BLOCK 256
#define FLOATS_PER_BLOCK (BLOCK * CH)          // 2560
#define VEC4_PER_BLOCK (FLOATS_PER_BLOCK / 4)  // 640

__global__ __launch_bounds__(BLOCK) void yolo_decode_kernel(
    const float* __restrict__ x,
    const int* __restrict__ img_size_p,
    float* __restrict__ out)
{
    // +1 pad (stride 11): gcd(11,32)=1 -> conflict-free LDS writes
    __shared__ float lds[BLOCK * (CH + 1)];

    const int tid = threadIdx.x;
    const long long cell_g = (long long)blockIdx.x * BLOCK + tid;

    const int plane = (int)(cell_g / GG);                  // b*NA + a
    const int cell  = (int)(cell_g - (long long)plane * GG);
    const int a  = plane % NA;
    const int gy = cell / GSZ;
    const int gx = cell - gy * GSZ;

    // img_size scalar: expected int32, but hedge against fp32 encoding.
    const int   iv = img_size_p[0];
    const float fv = __int_as_float(iv);
    const float img = (iv > 0 && iv < 100000) ? (float)iv : fv;
    const float stride = img / (float)GSZ;                 // 4.0 for 608/152

    const float aw[NA] = {11.0f, 24.0f, 42.0f};
    const float ah[NA] = {14.0f, 17.0f, 27.0f};

    // ---- coalesced planar reads: 10 loads, stride GG apart ----
    const long long base = (long long)plane * (CH * GG) + cell;
    float v[CH];
    #pragma unroll
    for (int c = 0; c < CH; ++c)
        v[c] = x[base + (long long)c * GG];

    // ---- decode ----
    float o[CH];
    o[0] = (1.0f / (1.0f + __expf(-v[0])) + (float)gx) * stride;       // bx
    o[1] = (1.0f / (1.0f + __expf(-v[1])) + (float)gy) * stride;       // by
    o[2] = (__expf(v[2]) * (aw[a] / stride)) * stride;                 // bw
    o[3] = (__expf(v[3]) * (ah[a] / stride)) * stride;                 // bh
    o[4] = v[4];                                                       // im
    o[5] = v[5];                                                       // re
    o[6] = 1.0f / (1.0f + __expf(-v[6]));                              // conf
    o[7] = 1.0f / (1.0f + __expf(-v[7]));                              // cls0
    o[8] = 1.0f / (1.0f + __expf(-v[8]));                              // cls1
    o[9] = 1.0f / (1.0f + __expf(-v[9]));                              // cls2

    // ---- stage to LDS (padded stride 11, conflict-free) ----
    #pragma unroll
    for (int k = 0; k < CH; ++k)
        lds[tid * (CH + 1) + k] = o[k];
    __syncthreads();

    // ---- contiguous float4 stores of the block's 10 KB output region ----
    float4* outv = (float4*)(out + (long long)blockIdx.x * FLOATS_PER_BLOCK);
    #pragma unroll
    for (int m = 0; m < 3; ++m) {
        int idx = m * BLOCK + tid;
        if (idx < VEC4_PER_BLOCK) {
            int j = idx * 4;
            float4 w;
            w.x = lds[((j    ) / CH) * (CH + 1) + ((j    ) % CH)];
            w.y = lds[((j + 1) / CH) * (CH + 1) + ((j + 1) % CH)];
            w.z = lds[((j + 2) / CH) * (CH + 1) + ((j + 2) % CH)];
            w.w = lds[((j + 3) / CH) * (CH + 1) + ((j + 3) % CH)];
            outv[idx] = w;
        }
    }
}

extern "C" void kernel_launch(void* const* d_in, const int* in_sizes, int n_in,
                              void* d_out, int out_size, void* d_ws, size_t ws_size,
                              hipStream_t stream)
{
    const float* x = (const float*)d_in[0];
    const int* img_size = (const int*)d_in[1];
    float* out = (float*)d_out;

    const long long total_cells = (long long)BATCH * NA * GG;  // 4,435,968
    const int grid = (int)(total_cells / BLOCK);               // 17328 exact

    yolo_decode_kernel<<<grid, BLOCK, 0, stream>>>(x, img_size, out);
}